// Round 7
// baseline (190.446 us; speedup 1.0000x reference)
//
#include <hip/hip_runtime.h>

#define NVAL 15
#define TPB  256
#define VPT  8   // float4 per thread, staged direct-to-LDS (zero data-VGPR cost)

typedef float fvec4 __attribute__((ext_vector_type(4)));

__device__ __forceinline__ fvec4 quant4(fvec4 v, const float* tf, float sc1, float k)
{
    float xs0 = v.x * sc1, xs1 = v.y * sc1, xs2 = v.z * sc1, xs3 = v.w * sc1;
    int c0 = 0, c1 = 0, c2 = 0, c3 = 0;
#pragma unroll
    for (int i = 0; i < NVAL; ++i) {
        float t = tf[i];
        c0 += (xs0 > t);   // strict > : searchsorted side="left"
        c1 += (xs1 > t);
        c2 += (xs2 > t);
        c3 += (xs3 > t);
    }
    fvec4 r;
    r.x = k * (float)c0;
    r.y = k * (float)c1;
    r.z = k * (float)c2;
    r.w = k * (float)c3;
    return r;
}

// R11: direct-to-LDS staging. R5 proved the VGPR file caps the register-burst
// at ~4 KB/wave (VPT=8 wanted >=50 live regs, RA serialized it at VGPR=36).
// global_load_lds width=16 issues the read burst with ZERO data VGPRs:
// 8 KB/wave genuinely outstanding at VGPR~30. Side benefit: the block becomes
// a pure-read phase then a pure compute+store phase — less fine-grained R/W
// interleave at the HBM controllers (fill kernel sustains 6.8 TB/s pure-write;
// mixed interleave is where we and rocclr's copyBuffer [2.55 TB/s] both lose).
// LDS dest rule (m104): wave-uniform base + lane*16 — layout below matches.
// 32 KB LDS/block -> 5 blocks/CU, 20 waves/CU. Grid 3136 exact-fit.
__global__ __launch_bounds__(TPB) void ltq_main(
    const float* __restrict__ x,
    const float* __restrict__ start,
    const float* __restrict__ a,
    const float* __restrict__ scale1,
    const float* __restrict__ scale2,
    float* __restrict__ out)
{
    __shared__ fvec4 lds4[TPB * VPT];                     // 32 KB
    const long long base = (long long)blockIdx.x * (TPB * VPT) + threadIdx.x;
    const fvec4* __restrict__ x4 = (const fvec4*)x + base;
    fvec4* __restrict__ o4 = (fvec4*)out + base;

    const int uni = threadIdx.x & ~63;   // wave-uniform lane-0 index within block

    // read phase: 8 direct-to-LDS loads per thread, no destination VGPRs.
    // lane l of wave w reads x4[block + j*TPB + w*64 + l] and HW writes
    // LDS at (uniform base &lds4[j*TPB + w*64]) + l*16B — same element. Linear.
#pragma unroll
    for (int j = 0; j < VPT; ++j) {
        __builtin_amdgcn_global_load_lds(
            (const __attribute__((address_space(1))) void*)(x4 + j * TPB),
            (__attribute__((address_space(3))) void*)(&lds4[j * TPB + uni]),
            16, 0, 0);
    }

    // threshold setup overlaps the in-flight loads
    const float s   = start[0];
    const float sc1 = scale1[0];
    const float k   = (float)(2.0 / 15.0) * scale2[0];
    float tf[NVAL];
    float cum = 0.0f;
#pragma unroll
    for (int i = 0; i < NVAL; ++i) {
        float ai = a[i];
        float ap = (ai > 1e-3f) ? ai : 1e-3f;   // jnp.where(a > EPS, a, EPS)
        tf[i] = (s + cum) + 0.5f * ap;          // tb[i] + a_pos[i]/2, exact fp32 association
        cum += ap;                              // sequential cumsum, matches np
    }

    __syncthreads();   // drains vmcnt(0) (global_load_lds) + barrier

    // compute+store phase: linear LDS reads (2-way bank alias = free), plain
    // stores (R9 A/B: NT stores regressed — LLC absorbs dirty out-lines).
#pragma unroll
    for (int j = 0; j < VPT; ++j) {
        fvec4 r = quant4(lds4[j * TPB + threadIdx.x], tf, sc1, k);
        o4[j * TPB] = r;
    }
}

// Generic tail (not launched when the main grid tiles n exactly — true here).
__global__ __launch_bounds__(256) void ltq_tail(
    const float* __restrict__ x,
    const float* __restrict__ start,
    const float* __restrict__ a,
    const float* __restrict__ scale1,
    const float* __restrict__ scale2,
    float* __restrict__ out,
    long long f4_done, long long n4, long long n)
{
    const float s   = start[0];
    const float sc1 = scale1[0];
    const float k   = (float)(2.0 / 15.0) * scale2[0];
    float tf[NVAL];
    float cum = 0.0f;
#pragma unroll
    for (int i = 0; i < NVAL; ++i) {
        float ai = a[i];
        float ap = (ai > 1e-3f) ? ai : 1e-3f;
        tf[i] = (s + cum) + 0.5f * ap;
        cum += ap;
    }

    const long long stride = (long long)gridDim.x * blockDim.x;
    const fvec4* __restrict__ x4 = (const fvec4*)x;
    fvec4* __restrict__ o4 = (fvec4*)out;
    for (long long i = f4_done + blockIdx.x * (long long)blockDim.x + threadIdx.x;
         i < n4; i += stride) {
        o4[i] = quant4(x4[i], tf, sc1, k);
    }
    for (long long i = (n4 << 2) + blockIdx.x * (long long)blockDim.x + threadIdx.x;
         i < n; i += stride) {
        float xs = x[i] * sc1;
        int c = 0;
#pragma unroll
        for (int t = 0; t < NVAL; ++t) c += (xs > tf[t]);
        out[i] = k * (float)c;
    }
}

extern "C" void kernel_launch(void* const* d_in, const int* in_sizes, int n_in,
                              void* d_out, int out_size, void* d_ws, size_t ws_size,
                              hipStream_t stream) {
    const float* x      = (const float*)d_in[0];
    const float* start  = (const float*)d_in[1];
    const float* a      = (const float*)d_in[2];
    const float* scale1 = (const float*)d_in[3];
    const float* scale2 = (const float*)d_in[4];
    float* out = (float*)d_out;

    const long long n  = in_sizes[0];
    const long long n4 = n >> 2;
    const long long per_block = (long long)TPB * VPT;      // float4s per block
    const long long blocks = n4 / per_block;               // exact-fit main grid

    if (blocks > 0) {
        // N=25,690,112 -> n4=6,422,528 -> 3136 blocks, zero remainder.
        ltq_main<<<(int)blocks, TPB, 0, stream>>>(x, start, a, scale1, scale2, out);
    }
    const long long f4_done = blocks * per_block;
    if (f4_done < n4 || (n & 3)) {
        ltq_tail<<<512, 256, 0, stream>>>(x, start, a, scale1, scale2, out,
                                          f4_done, n4, n);
    }
}

// Round 8
// 178.190 us; speedup vs baseline: 1.0688x; 1.0688x over previous
//
#include <hip/hip_runtime.h>

#define NVAL 15
#define TPB  256
#define VPT  4   // float4 loads per thread — champion burst depth (R6)

typedef float fvec4 __attribute__((ext_vector_type(4)));

__device__ __forceinline__ fvec4 quant4(fvec4 v, const float* tf, float sc1, float k)
{
    float xs0 = v.x * sc1, xs1 = v.y * sc1, xs2 = v.z * sc1, xs3 = v.w * sc1;
    int c0 = 0, c1 = 0, c2 = 0, c3 = 0;
#pragma unroll
    for (int i = 0; i < NVAL; ++i) {
        float t = tf[i];
        c0 += (xs0 > t);   // strict > : searchsorted side="left"
        c1 += (xs1 > t);
        c2 += (xs2 > t);
        c3 += (xs3 > t);
    }
    fvec4 r;
    r.x = k * (float)c0;
    r.y = k * (float)c1;
    r.z = k * (float)c2;
    r.w = k * (float)c3;
    return r;
}

// R12 — TERMINAL: revert to the R6 champion (178.1 µs total, best of 8
// measured configurations). Session A/B ledger:
//   load policy : NT wins (+~10 µs) — proven 3x (R5 plain, R11 LDS-plain both ~64 µs
//                 vs NT ~53 µs; FETCH_SIZE=50 MB signature identifies the plain path)
//   store policy: plain wins — R9 NT stores regressed ~+3 µs (LLC absorbs
//                 out's write-allocate lines during the kernel window)
//   burst depth : VPT=4 (VPT=8 overflows RA: VGPR=36 proves serialization)
//   block size  : TPB=256 (1024 regressed +6 µs)
//   structure   : single-shot exact-fit beats manual reg-pipeline (+9 µs),
//                 persistent grid-stride (+5 µs), and LDS staging (+12 µs)
// Kernel ~53 µs = 3.9 TB/s effective on 205.5 MB mixed R/W — 1.5x the
// platform's own rocclr copyBuffer (2.55 TB/s) in the same window.
__global__ __launch_bounds__(TPB) void ltq_main(
    const float* __restrict__ x,
    const float* __restrict__ start,
    const float* __restrict__ a,
    const float* __restrict__ scale1,
    const float* __restrict__ scale2,
    float* __restrict__ out)
{
    const long long base = (long long)blockIdx.x * (TPB * VPT) + threadIdx.x;
    const fvec4* __restrict__ x4 = (const fvec4*)x + base;
    fvec4* __restrict__ o4 = (fvec4*)out + base;

    fvec4 v[VPT];
#pragma unroll
    for (int j = 0; j < VPT; ++j)
        v[j] = __builtin_nontemporal_load(&x4[j * TPB]);  // NT: keep x out of LLC

    __builtin_amdgcn_sched_barrier(0);  // pin: all loads issued before any compute

    // threshold setup overlaps the in-flight loads
    const float s   = start[0];
    const float sc1 = scale1[0];
    const float k   = (float)(2.0 / 15.0) * scale2[0];
    float tf[NVAL];
    float cum = 0.0f;
#pragma unroll
    for (int i = 0; i < NVAL; ++i) {
        float ai = a[i];
        float ap = (ai > 1e-3f) ? ai : 1e-3f;   // jnp.where(a > EPS, a, EPS)
        tf[i] = (s + cum) + 0.5f * ap;          // tb[i] + a_pos[i]/2, exact fp32 association
        cum += ap;                              // sequential cumsum, matches np
    }

#pragma unroll
    for (int j = 0; j < VPT; ++j) {
        fvec4 r = quant4(v[j], tf, sc1, k);
        o4[j * TPB] = r;                         // plain store: LLC absorbs (R9 A/B)
    }
}

// Generic tail (not launched when the main grid tiles n exactly — true here).
__global__ __launch_bounds__(256) void ltq_tail(
    const float* __restrict__ x,
    const float* __restrict__ start,
    const float* __restrict__ a,
    const float* __restrict__ scale1,
    const float* __restrict__ scale2,
    float* __restrict__ out,
    long long f4_done, long long n4, long long n)
{
    const float s   = start[0];
    const float sc1 = scale1[0];
    const float k   = (float)(2.0 / 15.0) * scale2[0];
    float tf[NVAL];
    float cum = 0.0f;
#pragma unroll
    for (int i = 0; i < NVAL; ++i) {
        float ai = a[i];
        float ap = (ai > 1e-3f) ? ai : 1e-3f;
        tf[i] = (s + cum) + 0.5f * ap;
        cum += ap;
    }

    const long long stride = (long long)gridDim.x * blockDim.x;
    const fvec4* __restrict__ x4 = (const fvec4*)x;
    fvec4* __restrict__ o4 = (fvec4*)out;
    for (long long i = f4_done + blockIdx.x * (long long)blockDim.x + threadIdx.x;
         i < n4; i += stride) {
        o4[i] = quant4(x4[i], tf, sc1, k);
    }
    for (long long i = (n4 << 2) + blockIdx.x * (long long)blockDim.x + threadIdx.x;
         i < n; i += stride) {
        float xs = x[i] * sc1;
        int c = 0;
#pragma unroll
        for (int t = 0; t < NVAL; ++t) c += (xs > tf[t]);
        out[i] = k * (float)c;
    }
}

extern "C" void kernel_launch(void* const* d_in, const int* in_sizes, int n_in,
                              void* d_out, int out_size, void* d_ws, size_t ws_size,
                              hipStream_t stream) {
    const float* x      = (const float*)d_in[0];
    const float* start  = (const float*)d_in[1];
    const float* a      = (const float*)d_in[2];
    const float* scale1 = (const float*)d_in[3];
    const float* scale2 = (const float*)d_in[4];
    float* out = (float*)d_out;

    const long long n  = in_sizes[0];
    const long long n4 = n >> 2;
    const long long per_block = (long long)TPB * VPT;      // float4s per block
    const long long blocks = n4 / per_block;               // exact-fit main grid

    if (blocks > 0) {
        // N=25,690,112 -> n4=6,422,528 -> 6272 blocks, zero remainder.
        ltq_main<<<(int)blocks, TPB, 0, stream>>>(x, start, a, scale1, scale2, out);
    }
    const long long f4_done = blocks * per_block;
    if (f4_done < n4 || (n & 3)) {
        ltq_tail<<<512, 256, 0, stream>>>(x, start, a, scale1, scale2, out,
                                          f4_done, n4, n);
    }
}